// Round 4
// baseline (403.026 us; speedup 1.0000x reference)
//
#include <hip/hip_runtime.h>
#include <hip/hip_bf16.h>

#define B_SZ 1024
#define C_SZ 100
#define D_SZ 768

#define BM 128                 // d-rows per block (M-tile)
#define BN 128                 // b-cols per block (N-tile)
#define BK 64                  // e per K-step
#define NKT (D_SZ / BK)        // 12
#define NTHREADS 512           // 8 waves: 2 (M) x 4 (N), wave tile 64x32
#define TILES_PER_CLASS 48     // 6 M-tiles x 8 N-tiles

#define A_HALF (BM * BK)       // 8192 ushorts = 16KB per buffer
#define X_HALF (BN * BK)

typedef float f32x4 __attribute__((ext_vector_type(4)));
typedef short short8 __attribute__((ext_vector_type(8)));

__device__ __forceinline__ ushort f2bf(float f) {
    union { __hip_bfloat16 b; ushort u; } cv; cv.b = __float2bfloat16(f); return cv.u;
}
__device__ __forceinline__ float bf2f(ushort u) {
    union { __hip_bfloat16 b; ushort us; } cv; cv.us = u; return __bfloat162float(cv.b);
}
__device__ __forceinline__ void gload_lds16(const void* g, void* l) {
    __builtin_amdgcn_global_load_lds((const __attribute__((address_space(1))) void*)g,
                                     (__attribute__((address_space(3))) void*)l, 16, 0, 0);
}

#define N_A8 ((size_t)C_SZ * D_SZ * D_SZ / 8)     // A chunks of 8
#define N_R8 ((size_t)B_SZ * D_SZ / 8)            // raw chunks of 8

// prepass: inv f32 -> bf16, raw f32 -> bf16, into ws (contiguous)
__global__ __launch_bounds__(256) void conv_bf16(const float* __restrict__ inv,
                                                 const float* __restrict__ raw,
                                                 ushort* __restrict__ ws) {
    const size_t n8 = N_A8 + N_R8;
    for (size_t i = (size_t)blockIdx.x * 256 + threadIdx.x; i < n8;
         i += (size_t)gridDim.x * 256) {
        const float* src = (i < N_A8) ? (inv + i * 8) : (raw + (i - N_A8) * 8);
        const f32x4 v0 = *(const f32x4*)src;
        const f32x4 v1 = *(const f32x4*)(src + 4);
        short8 p;
        p[0]=(short)f2bf(v0.x); p[1]=(short)f2bf(v0.y); p[2]=(short)f2bf(v0.z); p[3]=(short)f2bf(v0.w);
        p[4]=(short)f2bf(v1.x); p[5]=(short)f2bf(v1.y); p[6]=(short)f2bf(v1.z); p[7]=(short)f2bf(v1.w);
        *(short8*)(ws + i * 8) = p;
    }
}

template <int AMODE>
__global__ __launch_bounds__(NTHREADS, 4) void fecam_scores(
        const float* __restrict__ raw, const float* __restrict__ mean,
        const float* __restrict__ inv, const float* __restrict__ diag,
        const ushort* __restrict__ wsA, const ushort* __restrict__ rawbf,
        float* __restrict__ out) {
    __shared__ __align__(16) ushort aLds[2 * A_HALF];   // 32 KB (fold tile reuses)
    __shared__ __align__(16) ushort xLds[2 * X_HALF];   // 32 KB
    __shared__ float red[8 * 32];                       //  1 KB

    const int tid = (int)threadIdx.x;
    const int bx  = (int)blockIdx.x;

    // XCD-pinned, class-major grouping (kept from R3: FETCH ~= A read once)
    const int x = bx & 7;
    const int slot = bx >> 3;
    const int nCls  = (x < 4) ? 13 : 12;
    const int baseC = (x < 4) ? x * 13 : 52 + (x - 4) * 12;
    const int ci = slot / TILES_PER_CLASS;
    if (ci >= nCls) return;
    const int t  = slot % TILES_PER_CLASS;
    const int c  = baseC + ci;
    const int d0 = (t >> 3) * BM;
    const int b0 = (t & 7) * BN;

    const int lane = tid & 63;
    const int wid  = tid >> 6;
    const int wm   = wid >> 2;      // 0..1  (M)
    const int wn   = wid & 3;       // 0..3  (N)
    const int l15  = lane & 15;
    const int l4   = lane >> 4;

    const ushort* Abf = wsA + (size_t)c * D_SZ * D_SZ;
    const float*  Af  = inv + (size_t)c * D_SZ * D_SZ;
    const float*  mc  = mean + (size_t)c * D_SZ;
    const float*  dc  = diag + (size_t)c * D_SZ;

    // ---- staging helpers (XOR swizzle on SOURCE chunk; LDS dest linear) ----
    auto stage_a = [&](ushort* dst, int e0) {
        #pragma unroll
        for (int i = 0; i < 2; ++i) {
            const int s = tid + i * NTHREADS;       // 16B slot
            const int r = s >> 3;                   // local d-row
            const int qg = (s & 7) ^ (r & 7);       // source e-chunk
            if constexpr (AMODE == 1) {
                gload_lds16(Abf + (size_t)(d0 + r) * D_SZ + e0 + qg * 8, dst + s * 8);
            } else {
                const float* gp = Af + (size_t)(d0 + r) * D_SZ + e0 + qg * 8;
                const f32x4 a0 = *(const f32x4*)gp;
                const f32x4 a1 = *(const f32x4*)(gp + 4);
                short8 p;
                p[0]=(short)f2bf(a0.x); p[1]=(short)f2bf(a0.y); p[2]=(short)f2bf(a0.z); p[3]=(short)f2bf(a0.w);
                p[4]=(short)f2bf(a1.x); p[5]=(short)f2bf(a1.y); p[6]=(short)f2bf(a1.z); p[7]=(short)f2bf(a1.w);
                *(short8*)(dst + s * 8) = p;
            }
        }
    };
    auto stage_x = [&](ushort* dst, int e0) {
        #pragma unroll
        for (int i = 0; i < 2; ++i) {
            const int s = tid + i * NTHREADS;
            const int r = s >> 3;                   // local b-row
            const int qg = (s & 7) ^ (r & 7);
            const int e = e0 + qg * 8;
            float xv[8];
            if constexpr (AMODE == 1) {
                const short8 rb = *(const short8*)(rawbf + (size_t)(b0 + r) * D_SZ + e);
                #pragma unroll
                for (int jj = 0; jj < 8; ++jj) xv[jj] = bf2f((ushort)rb[jj]);
            } else {
                const f32x4 r0 = *(const f32x4*)(raw + (size_t)(b0 + r) * D_SZ + e);
                const f32x4 r1 = *(const f32x4*)(raw + (size_t)(b0 + r) * D_SZ + e + 4);
                xv[0]=r0.x; xv[1]=r0.y; xv[2]=r0.z; xv[3]=r0.w;
                xv[4]=r1.x; xv[5]=r1.y; xv[6]=r1.z; xv[7]=r1.w;
            }
            const f32x4 m0 = *(const f32x4*)(mc + e);
            const f32x4 m1 = *(const f32x4*)(mc + e + 4);
            const f32x4 g0 = *(const f32x4*)(dc + e);
            const f32x4 g1 = *(const f32x4*)(dc + e + 4);
            short8 p;
            p[0]=(short)f2bf((xv[0]-m0.x)/g0.x); p[1]=(short)f2bf((xv[1]-m0.y)/g0.y);
            p[2]=(short)f2bf((xv[2]-m0.z)/g0.z); p[3]=(short)f2bf((xv[3]-m0.w)/g0.w);
            p[4]=(short)f2bf((xv[4]-m1.x)/g1.x); p[5]=(short)f2bf((xv[5]-m1.y)/g1.y);
            p[6]=(short)f2bf((xv[6]-m1.z)/g1.z); p[7]=(short)f2bf((xv[7]-m1.w)/g1.w);
            *(short8*)(dst + s * 8) = p;
        }
    };

    // ---- prologue + K-loop (2-phase, dbuf, one barrier per step) ----
    stage_a(aLds, 0);
    stage_x(xLds, 0);
    __syncthreads();

    f32x4 acc[4][2] = {};   // wave 64(M) x 32(N): m-frags 4, n-frags 2

    for (int kt = 0; kt < NKT; ++kt) {
        const int cur = kt & 1;
        if (kt + 1 < NKT) stage_a(aLds + (cur ^ 1) * A_HALF, (kt + 1) * BK);
        const ushort* ab = aLds + cur * A_HALF;
        const ushort* xb = xLds + cur * X_HALF;
        #pragma unroll
        for (int kk = 0; kk < 2; ++kk) {
            short8 xf[2];
            #pragma unroll
            for (int n = 0; n < 2; ++n) {
                const int xr = wn * 32 + n * 16 + l15;
                const int ch = (kk * 4 + l4) ^ (xr & 7);
                xf[n] = *(const short8*)(xb + xr * 64 + ch * 8);
            }
            #pragma unroll
            for (int m = 0; m < 4; ++m) {
                const int ar = wm * 64 + m * 16 + l15;
                const int ch = (kk * 4 + l4) ^ (ar & 7);
                const short8 af = *(const short8*)(ab + ar * 64 + ch * 8);
                #pragma unroll
                for (int n = 0; n < 2; ++n)
                    acc[m][n] = __builtin_amdgcn_mfma_f32_16x16x32_bf16(af, xf[n], acc[m][n], 0, 0, 0);
            }
        }
        if (kt + 1 < NKT) stage_x(xLds + (cur ^ 1) * X_HALF, (kt + 1) * BK);
        __syncthreads();
    }

    // ---- fold tile: x[b 128][d-range 128] bf16, swizzled, reuses aLds ----
    ushort* fbuf = aLds;
    #pragma unroll
    for (int i = 0; i < 4; ++i) {
        const int s = tid + i * NTHREADS;   // 16B slot: 128 rows x 16 chunks
        const int r = s >> 4;               // local b-row
        const int q = s & 15;
        const int qg = q ^ (r & 15);        // source d-chunk
        const int dcol = d0 + qg * 8;
        float xv[8];
        if constexpr (AMODE == 1) {
            const short8 rb = *(const short8*)(rawbf + (size_t)(b0 + r) * D_SZ + dcol);
            #pragma unroll
            for (int jj = 0; jj < 8; ++jj) xv[jj] = bf2f((ushort)rb[jj]);
        } else {
            const f32x4 r0 = *(const f32x4*)(raw + (size_t)(b0 + r) * D_SZ + dcol);
            const f32x4 r1 = *(const f32x4*)(raw + (size_t)(b0 + r) * D_SZ + dcol + 4);
            xv[0]=r0.x; xv[1]=r0.y; xv[2]=r0.z; xv[3]=r0.w;
            xv[4]=r1.x; xv[5]=r1.y; xv[6]=r1.z; xv[7]=r1.w;
        }
        const f32x4 m0 = *(const f32x4*)(mc + dcol);
        const f32x4 m1 = *(const f32x4*)(mc + dcol + 4);
        const f32x4 g0 = *(const f32x4*)(dc + dcol);
        const f32x4 g1 = *(const f32x4*)(dc + dcol + 4);
        short8 p;
        p[0]=(short)f2bf((xv[0]-m0.x)/g0.x); p[1]=(short)f2bf((xv[1]-m0.y)/g0.y);
        p[2]=(short)f2bf((xv[2]-m0.z)/g0.z); p[3]=(short)f2bf((xv[3]-m0.w)/g0.w);
        p[4]=(short)f2bf((xv[4]-m1.x)/g1.x); p[5]=(short)f2bf((xv[5]-m1.y)/g1.y);
        p[6]=(short)f2bf((xv[6]-m1.z)/g1.z); p[7]=(short)f2bf((xv[7]-m1.w)/g1.w);
        *(short8*)(fbuf + r * 128 + q * 8) = p;
    }
    __syncthreads();

    // ---- fold: v[n] = sum over this block's d-range of temp'[d,b]*x[b,d] ----
    // C/D layout: col(b) = l15, row(d) = l4*4 + j
    float v[2] = {0.f, 0.f};
    #pragma unroll
    for (int m = 0; m < 4; ++m) {
        const int g  = wm * 16 + m * 4 + l4;   // 8B granule index in d (0..31)
        const int qc = g >> 1;
        const int h  = g & 1;
        #pragma unroll
        for (int n = 0; n < 2; ++n) {
            const int bl = wn * 32 + n * 16 + l15;
            const int qd = qc ^ (bl & 15);
            const ushort4 x4 = *(const ushort4*)(fbuf + bl * 128 + qd * 8 + h * 4);
            v[n] += acc[m][n][0] * bf2f(x4.x);
            v[n] += acc[m][n][1] * bf2f(x4.y);
            v[n] += acc[m][n][2] * bf2f(x4.z);
            v[n] += acc[m][n][3] * bf2f(x4.w);
        }
    }
    #pragma unroll
    for (int n = 0; n < 2; ++n) {
        v[n] += __shfl_xor(v[n], 16);
        v[n] += __shfl_xor(v[n], 32);
    }
    if (lane < 16) {
        red[wid * 32 + l15]      = v[0];
        red[wid * 32 + 16 + l15] = v[1];
    }
    __syncthreads();
    if (tid < BN) {
        const int wnn = tid >> 5;
        const int off = tid & 31;
        const float p = red[wnn * 32 + off] + red[(wnn + 4) * 32 + off];
        atomicAdd(out + (size_t)(b0 + tid) * C_SZ + c, -p);
    }
}

extern "C" void kernel_launch(void* const* d_in, const int* in_sizes, int n_in,
                              void* d_out, int out_size, void* d_ws, size_t ws_size,
                              hipStream_t stream) {
    const float* raw  = (const float*)d_in[0];
    const float* mean = (const float*)d_in[1];
    const float* inv  = (const float*)d_in[2];
    const float* diag = (const float*)d_in[3];
    float* out = (float*)d_out;
    const size_t need = (N_A8 + N_R8) * 8 * sizeof(ushort);
    hipMemsetAsync(d_out, 0, (size_t)out_size * sizeof(float), stream);
    dim3 grid(8 * 13 * TILES_PER_CLASS);   // 4992 (12-class XCDs early-exit tail)
    if (ws_size >= need) {
        ushort* ws = (ushort*)d_ws;
        conv_bf16<<<2048, 256, 0, stream>>>(inv, raw, ws);
        fecam_scores<1><<<grid, NTHREADS, 0, stream>>>(raw, mean, inv, diag,
                                                       ws, ws + N_A8 * 8, out);
    } else {
        fecam_scores<0><<<grid, NTHREADS, 0, stream>>>(raw, mean, inv, diag,
                                                       nullptr, nullptr, out);
    }
}

// Round 5
// 306.495 us; speedup vs baseline: 1.3150x; 1.3150x over previous
//
#include <hip/hip_runtime.h>
#include <hip/hip_bf16.h>

#define B_SZ 1024
#define C_SZ 100
#define D_SZ 768

#define BM 128                 // d-rows per block (M)
#define BN 256                 // b-cols per block (N)
#define BK 32                  // e per K-step
#define NKT (D_SZ / BK)        // 24
#define NTHREADS 512           // 8 waves: 2(M) x 4(N), wave tile 64x64
#define TILES_PER_CLASS 24     // 6 M-tiles x 4 N-tiles

#define A_HALF (BM * BK)       // 4096 ushorts = 8 KB / buffer
#define X_HALF (BN * BK)       // 8192 ushorts = 16 KB / buffer

#define TBL_ELEMS ((size_t)C_SZ * D_SZ)                  // 76,800
#define A_ELEMS   ((size_t)C_SZ * D_SZ * D_SZ)           // 58,982,400
#define XN_ELEMS  ((size_t)C_SZ * B_SZ * D_SZ)           // 78,643,200

typedef float f32x4 __attribute__((ext_vector_type(4)));
typedef short short8 __attribute__((ext_vector_type(8)));

__device__ __forceinline__ ushort f2bf(float f) {
    union { __hip_bfloat16 b; ushort u; } cv; cv.b = __float2bfloat16(f); return cv.u;
}
__device__ __forceinline__ float bf2f(ushort u) {
    union { __hip_bfloat16 b; ushort us; } cv; cv.us = u; return __bfloat162float(cv.b);
}
__device__ __forceinline__ void gload_lds16(const void* g, void* l) {
    __builtin_amdgcn_global_load_lds((const __attribute__((address_space(1))) void*)g,
                                     (__attribute__((address_space(3))) void*)l, 16, 0, 0);
}

// ---- prepass 1: rd = 1/diag, md = mean*rd (f32 tables, 0.6 MB) ----
__global__ __launch_bounds__(256) void make_tables(const float* __restrict__ mean,
                                                   const float* __restrict__ diag,
                                                   float* __restrict__ rd,
                                                   float* __restrict__ md) {
    const int i = ((int)blockIdx.x * 256 + (int)threadIdx.x) * 4;
    if (i < (int)TBL_ELEMS) {
        const f32x4 dv = *(const f32x4*)(diag + i);
        const f32x4 mv = *(const f32x4*)(mean + i);
        f32x4 r, m;
        r.x = 1.0f / dv.x; r.y = 1.0f / dv.y; r.z = 1.0f / dv.z; r.w = 1.0f / dv.w;
        m.x = mv.x * r.x;  m.y = mv.y * r.y;  m.z = mv.z * r.z;  m.w = mv.w * r.w;
        *(f32x4*)(rd + i) = r;
        *(f32x4*)(md + i) = m;
    }
}

// ---- prepass 2: inv f32 -> bf16 ----
__global__ __launch_bounds__(256) void conv_a_bf16(const float* __restrict__ inv,
                                                   ushort* __restrict__ Abf) {
    const size_t n8 = A_ELEMS / 8;
    for (size_t i = (size_t)blockIdx.x * 256 + threadIdx.x; i < n8;
         i += (size_t)gridDim.x * 256) {
        const f32x4 v0 = *(const f32x4*)(inv + i * 8);
        const f32x4 v1 = *(const f32x4*)(inv + i * 8 + 4);
        short8 p;
        p[0]=(short)f2bf(v0.x); p[1]=(short)f2bf(v0.y); p[2]=(short)f2bf(v0.z); p[3]=(short)f2bf(v0.w);
        p[4]=(short)f2bf(v1.x); p[5]=(short)f2bf(v1.y); p[6]=(short)f2bf(v1.z); p[7]=(short)f2bf(v1.w);
        *(short8*)(Abf + i * 8) = p;
    }
}

// ---- prepass 3 (MODE 2): xn[c][b][d] = raw*rd - md, bf16 ----
__global__ __launch_bounds__(256) void conv_xn(const float* __restrict__ raw,
                                               const float* __restrict__ rd,
                                               const float* __restrict__ md,
                                               ushort* __restrict__ xn) {
    const int CPC = B_SZ * D_SZ / 8;        // 98304 chunks/class
    const size_t n8 = XN_ELEMS / 8;
    for (size_t i = (size_t)blockIdx.x * 256 + threadIdx.x; i < n8;
         i += (size_t)gridDim.x * 256) {
        const int c   = (int)(i / CPC);
        const int rem = (int)(i - (size_t)c * CPC);
        const int dch = rem % (D_SZ / 8);
        const float* rp = raw + (size_t)rem * 8;
        const float* rdp = rd + (size_t)c * D_SZ + dch * 8;
        const float* mdp = md + (size_t)c * D_SZ + dch * 8;
        const f32x4 r0 = *(const f32x4*)rp,        r1 = *(const f32x4*)(rp + 4);
        const f32x4 d0 = *(const f32x4*)rdp,       d1 = *(const f32x4*)(rdp + 4);
        const f32x4 m0 = *(const f32x4*)mdp,       m1 = *(const f32x4*)(mdp + 4);
        short8 p;
        p[0]=(short)f2bf(r0.x*d0.x - m0.x); p[1]=(short)f2bf(r0.y*d0.y - m0.y);
        p[2]=(short)f2bf(r0.z*d0.z - m0.z); p[3]=(short)f2bf(r0.w*d0.w - m0.w);
        p[4]=(short)f2bf(r1.x*d1.x - m1.x); p[5]=(short)f2bf(r1.y*d1.y - m1.y);
        p[6]=(short)f2bf(r1.z*d1.z - m1.z); p[7]=(short)f2bf(r1.w*d1.w - m1.w);
        *(short8*)(xn + i * 8) = p;
    }
}

// MODE 2: A gload_lds + xn gload_lds (zero VALU staging)
// MODE 1: A gload_lds + X = raw*rd - md (1 fma/elem)
// MODE 0: no ws — all f32, divide (correctness fallback)
template <int MODE>
__global__ __launch_bounds__(NTHREADS, 4) void fecam_scores(
        const float* __restrict__ raw, const float* __restrict__ mean,
        const float* __restrict__ diag, const float* __restrict__ inv,
        const float* __restrict__ rdT, const float* __restrict__ mdT,
        const ushort* __restrict__ AbfAll, const ushort* __restrict__ xnAll,
        float* __restrict__ out) {
    __shared__ __align__(16) ushort aLds[2 * A_HALF];   // 16 KB
    __shared__ __align__(16) ushort xLds[2 * X_HALF];   // 32 KB
    __shared__ float red[8 * 64];                       //  2 KB

    const int tid = (int)threadIdx.x;
    const int bx  = (int)blockIdx.x;

    // XCD-pinned class grouping (R3: A read from HBM ~once)
    const int x = bx & 7;
    const int slot = bx >> 3;
    const int nCls  = (x < 4) ? 13 : 12;
    const int baseC = (x < 4) ? x * 13 : 52 + (x - 4) * 12;
    const int ci = slot / TILES_PER_CLASS;
    if (ci >= nCls) return;
    const int t  = slot % TILES_PER_CLASS;
    const int c  = baseC + ci;
    const int d0 = (t >> 2) * BM;
    const int b0 = (t & 3) * BN;

    const int lane = tid & 63;
    const int wid  = tid >> 6;
    const int wm   = wid >> 2;      // 0..1 (M)
    const int wn   = wid & 3;       // 0..3 (N)
    const int l15  = lane & 15;
    const int l4   = lane >> 4;

    const ushort* Abf = AbfAll + (size_t)c * D_SZ * D_SZ;
    const ushort* xnc = xnAll + (size_t)c * B_SZ * D_SZ;
    const float*  Af  = inv + (size_t)c * D_SZ * D_SZ;

    // ---- staging (source-side XOR swizzle, LDS dest linear; rule 21) ----
    auto stage_a = [&](ushort* dst, int e0) {
        const int s = tid;                    // 512 slots: 128 rows x 4 granules
        const int r = s >> 2;
        const int q = (s & 3) ^ (r & 3);      // source e-chunk
        if constexpr (MODE >= 1) {
            gload_lds16(Abf + (size_t)(d0 + r) * D_SZ + e0 + q * 8, dst + s * 8);
        } else {
            const float* gp = Af + (size_t)(d0 + r) * D_SZ + e0 + q * 8;
            const f32x4 a0 = *(const f32x4*)gp;
            const f32x4 a1 = *(const f32x4*)(gp + 4);
            short8 p;
            p[0]=(short)f2bf(a0.x); p[1]=(short)f2bf(a0.y); p[2]=(short)f2bf(a0.z); p[3]=(short)f2bf(a0.w);
            p[4]=(short)f2bf(a1.x); p[5]=(short)f2bf(a1.y); p[6]=(short)f2bf(a1.z); p[7]=(short)f2bf(a1.w);
            *(short8*)(dst + s * 8) = p;
        }
    };
    auto stage_x = [&](ushort* dst, int e0) {
        #pragma unroll
        for (int i = 0; i < 2; ++i) {
            const int s = tid + i * NTHREADS;  // 1024 slots: 256 rows x 4 granules
            const int r = s >> 2;
            const int q = (s & 3) ^ (r & 3);
            const int e = e0 + q * 8;
            if constexpr (MODE == 2) {
                gload_lds16(xnc + (size_t)(b0 + r) * D_SZ + e, dst + s * 8);
            } else {
                const float* rp = raw + (size_t)(b0 + r) * D_SZ + e;
                const f32x4 r0 = *(const f32x4*)rp, r1 = *(const f32x4*)(rp + 4);
                float xv[8];
                if constexpr (MODE == 1) {
                    const f32x4 dd0 = *(const f32x4*)(rdT + (size_t)c * D_SZ + e);
                    const f32x4 dd1 = *(const f32x4*)(rdT + (size_t)c * D_SZ + e + 4);
                    const f32x4 mm0 = *(const f32x4*)(mdT + (size_t)c * D_SZ + e);
                    const f32x4 mm1 = *(const f32x4*)(mdT + (size_t)c * D_SZ + e + 4);
                    xv[0]=r0.x*dd0.x-mm0.x; xv[1]=r0.y*dd0.y-mm0.y; xv[2]=r0.z*dd0.z-mm0.z; xv[3]=r0.w*dd0.w-mm0.w;
                    xv[4]=r1.x*dd1.x-mm1.x; xv[5]=r1.y*dd1.y-mm1.y; xv[6]=r1.z*dd1.z-mm1.z; xv[7]=r1.w*dd1.w-mm1.w;
                } else {
                    const f32x4 mm0 = *(const f32x4*)(mean + (size_t)c * D_SZ + e);
                    const f32x4 mm1 = *(const f32x4*)(mean + (size_t)c * D_SZ + e + 4);
                    const f32x4 gg0 = *(const f32x4*)(diag + (size_t)c * D_SZ + e);
                    const f32x4 gg1 = *(const f32x4*)(diag + (size_t)c * D_SZ + e + 4);
                    xv[0]=(r0.x-mm0.x)/gg0.x; xv[1]=(r0.y-mm0.y)/gg0.y; xv[2]=(r0.z-mm0.z)/gg0.z; xv[3]=(r0.w-mm0.w)/gg0.w;
                    xv[4]=(r1.x-mm1.x)/gg1.x; xv[5]=(r1.y-mm1.y)/gg1.y; xv[6]=(r1.z-mm1.z)/gg1.z; xv[7]=(r1.w-mm1.w)/gg1.w;
                }
                short8 p;
                #pragma unroll
                for (int jj = 0; jj < 8; ++jj) p[jj] = (short)f2bf(xv[jj]);
                *(short8*)(dst + s * 8) = p;
            }
        }
    };

    stage_a(aLds, 0);
    stage_x(xLds, 0);
    __syncthreads();

    f32x4 acc[4][4] = {};   // wave 64(M) x 64(N)

    const int fch = l4 ^ (l15 & 3);   // fragment chunk (matches source swizzle)
    for (int kt = 0; kt < NKT; ++kt) {
        const int cur = kt & 1;
        if (kt + 1 < NKT) {
            stage_a(aLds + (cur ^ 1) * A_HALF, (kt + 1) * BK);
            stage_x(xLds + (cur ^ 1) * X_HALF, (kt + 1) * BK);
        }
        const ushort* ab = aLds + cur * A_HALF;
        const ushort* xb = xLds + cur * X_HALF;
        short8 xf[4];
        #pragma unroll
        for (int n = 0; n < 4; ++n)
            xf[n] = *(const short8*)(xb + ((wn * 64 + n * 16 + l15) * 4 + fch) * 8);
        #pragma unroll
        for (int m = 0; m < 4; ++m) {
            const short8 af = *(const short8*)(ab + ((wm * 64 + m * 16 + l15) * 4 + fch) * 8);
            #pragma unroll
            for (int n = 0; n < 4; ++n)
                acc[m][n] = __builtin_amdgcn_mfma_f32_16x16x32_bf16(af, xf[n], acc[m][n], 0, 0, 0);
        }
        __syncthreads();
    }

    // ---- fold: v[n] = sum_d temp'[d,b] * x[b,d] (direct global gathers) ----
    // C/D layout: col(b)=l15, row(d)=l4*4+j
    float v[4] = {};
    #pragma unroll
    for (int m = 0; m < 4; ++m) {
        const int dd = d0 + wm * 64 + m * 16 + l4 * 4;
        #pragma unroll
        for (int n = 0; n < 4; ++n) {
            const int bl = b0 + wn * 64 + n * 16 + l15;
            float xv[4];
            if constexpr (MODE == 2) {
                const ushort4 x4 = *(const ushort4*)(xnc + (size_t)bl * D_SZ + dd);
                xv[0]=bf2f(x4.x); xv[1]=bf2f(x4.y); xv[2]=bf2f(x4.z); xv[3]=bf2f(x4.w);
            } else if constexpr (MODE == 1) {
                const f32x4 rv = *(const f32x4*)(raw + (size_t)bl * D_SZ + dd);
                const f32x4 dd4 = *(const f32x4*)(rdT + (size_t)c * D_SZ + dd);
                const f32x4 mm4 = *(const f32x4*)(mdT + (size_t)c * D_SZ + dd);
                xv[0]=rv.x*dd4.x-mm4.x; xv[1]=rv.y*dd4.y-mm4.y;
                xv[2]=rv.z*dd4.z-mm4.z; xv[3]=rv.w*dd4.w-mm4.w;
            } else {
                const f32x4 rv = *(const f32x4*)(raw + (size_t)bl * D_SZ + dd);
                const f32x4 mm4 = *(const f32x4*)(mean + (size_t)c * D_SZ + dd);
                const f32x4 gg4 = *(const f32x4*)(diag + (size_t)c * D_SZ + dd);
                xv[0]=(rv.x-mm4.x)/gg4.x; xv[1]=(rv.y-mm4.y)/gg4.y;
                xv[2]=(rv.z-mm4.z)/gg4.z; xv[3]=(rv.w-mm4.w)/gg4.w;
            }
            v[n] += acc[m][n][0]*xv[0] + acc[m][n][1]*xv[1]
                  + acc[m][n][2]*xv[2] + acc[m][n][3]*xv[3];
        }
    }
    #pragma unroll
    for (int n = 0; n < 4; ++n) {
        v[n] += __shfl_xor(v[n], 16);
        v[n] += __shfl_xor(v[n], 32);
    }
    if (lane < 16) {
        #pragma unroll
        for (int n = 0; n < 4; ++n) red[wid * 64 + n * 16 + l15] = v[n];
    }
    __syncthreads();
    if (tid < BN) {   // b-local = tid: wn=tid>>6, n=(tid>>4)&3, l=tid&15
        const int wno = tid >> 6;
        const int off = tid & 63;
        const float p = red[wno * 64 + off] + red[(4 + wno) * 64 + off];
        atomicAdd(out + (size_t)(b0 + tid) * C_SZ + c, -p);
    }
}

extern "C" void kernel_launch(void* const* d_in, const int* in_sizes, int n_in,
                              void* d_out, int out_size, void* d_ws, size_t ws_size,
                              hipStream_t stream) {
    const float* raw  = (const float*)d_in[0];
    const float* mean = (const float*)d_in[1];
    const float* inv  = (const float*)d_in[2];
    const float* diag = (const float*)d_in[3];
    float* out = (float*)d_out;

    const size_t TBL_B = TBL_ELEMS * 4;                 // 307,200 each
    const size_t A_B   = A_ELEMS * 2;                   // 117,964,800
    const size_t XN_B  = XN_ELEMS * 2;                  // 157,286,400
    const size_t need1 = 2 * TBL_B + A_B;               // 118.6 MB
    const size_t need2 = need1 + XN_B;                  // 275.9 MB

    hipMemsetAsync(d_out, 0, (size_t)out_size * sizeof(float), stream);
    dim3 grid(8 * 13 * TILES_PER_CLASS);                // 2496

    float*  rdT = (float*)d_ws;
    float*  mdT = (float*)((char*)d_ws + TBL_B);
    ushort* Abf = (ushort*)((char*)d_ws + 2 * TBL_B);
    ushort* xn  = (ushort*)((char*)d_ws + need1);

    if (ws_size >= need2) {
        make_tables<<<75, 256, 0, stream>>>(mean, diag, rdT, mdT);
        conv_a_bf16<<<2048, 256, 0, stream>>>(inv, Abf);
        conv_xn<<<2048, 256, 0, stream>>>(raw, rdT, mdT, xn);
        fecam_scores<2><<<grid, NTHREADS, 0, stream>>>(raw, mean, diag, inv, rdT, mdT, Abf, xn, out);
    } else if (ws_size >= need1) {
        make_tables<<<75, 256, 0, stream>>>(mean, diag, rdT, mdT);
        conv_a_bf16<<<2048, 256, 0, stream>>>(inv, Abf);
        fecam_scores<1><<<grid, NTHREADS, 0, stream>>>(raw, mean, diag, inv, rdT, mdT, Abf, nullptr, out);
    } else {
        fecam_scores<0><<<grid, NTHREADS, 0, stream>>>(raw, mean, diag, inv, nullptr, nullptr, nullptr, nullptr, out);
    }
}